// Round 2
// baseline (4632.729 us; speedup 1.0000x reference)
//
#include <hip/hip_runtime.h>

typedef _Float16 f16;
typedef _Float16 f16x8 __attribute__((ext_vector_type(8)));
typedef float f32x4 __attribute__((ext_vector_type(4)));

#define MFMA16(a, b, c) __builtin_amdgcn_mfma_f32_16x16x32_f16((a), (b), (c), 0, 0, 0)

__device__ __forceinline__ float sigmoidf_(float x) { return 1.f / (1.f + __expf(-x)); }
__device__ __forceinline__ float tanhf_(float x) { return 1.f - 2.f / (__expf(2.f * x) + 1.f); }

// ---------------- workspace layout (bytes) ----------------
// packed fp16 weights (element offsets within pk):
//   inW 0 | e0 16384 | e1 344064 | d0i 868352 | d0h 933888 | d1 950272 | out 983040 | end 999424
#define PK_BYTES   1998848
#define BIAS_OFF   1998848   // 2560 floats: be0[1024] be1[1024] bd0[256] bd1[256]
#define H0_OFF     2009088   // 1024*100*64 f16
#define H1_OFF     15116288  // 1024*100*256 f16
#define Z_OFF      67545088  // 1024*256 f16

// Fragment-major packed weight index: group = (nt*KT + kt)*64 + lane, 8 f16 per group.
// n = nt*16 + (lane&15), k = kt*32 + (lane>>4)*8 + j   (matches gfx950 16x16x32 A/B layout)

__global__ __launch_bounds__(256) void pack_kernel(
    const float* inW,
    const float* e0i, const float* e0h, const float* e1i, const float* e1h,
    const float* d0i, const float* d0h, const float* d1i, const float* d1h,
    const float* outW,
    const float* eb0i, const float* eb0h, const float* eb1i, const float* eb1h,
    const float* db0i, const float* db0h, const float* db1i, const float* db1h,
    f16* pk, float* bias_ws)
{
    int t = blockIdx.x * 256 + threadIdx.x;
    if (t < 124928) {
        int g = t; int KT, ka, kb; const float* A; const float* B; long doff;
        if (g < 2048)        {              KT = 8;  ka = 256; kb = 0;   A = inW;  B = nullptr; doff = 0; }
        else if (g < 43008)  { g -= 2048;   KT = 10; ka = 64;  kb = 256; A = e0i;  B = e0h;     doff = 16384; }
        else if (g < 108544) { g -= 43008;  KT = 16; ka = 256; kb = 256; A = e1i;  B = e1h;     doff = 344064; }
        else if (g < 116736) { g -= 108544; KT = 8;  ka = 256; kb = 0;   A = d0i;  B = nullptr; doff = 868352; }
        else if (g < 118784) { g -= 116736; KT = 2;  ka = 64;  kb = 0;   A = d0h;  B = nullptr; doff = 933888; }
        else if (g < 122880) { g -= 118784; KT = 4;  ka = 64;  kb = 64;  A = d1i;  B = d1h;     doff = 950272; }
        else                 { g -= 122880; KT = 2;  ka = 64;  kb = 0;   A = outW; B = nullptr; doff = 983040; }
        int lane = g & 63; int gk = g >> 6;
        int kt = gk % KT;  int nt = gk / KT;
        int n  = nt * 16 + (lane & 15);
        int k0 = kt * 32 + (lane >> 4) * 8;
        f16x8 v;
        #pragma unroll
        for (int j = 0; j < 8; ++j) {
            int k = k0 + j;
            float s = (k < ka) ? A[(long)n * ka + k] : B[(long)n * kb + (k - ka)];
            v[j] = (f16)s;
        }
        *(f16x8*)(pk + doff + (long)g * 8) = v;
    } else {
        int i = t - 124928;
        if (i < 1024)      bias_ws[i] = eb0i[i] + eb0h[i];
        else if (i < 2048) bias_ws[i] = eb1i[i - 1024] + eb1h[i - 1024];
        else if (i < 2304) bias_ws[i] = db0i[i - 2048] + db0h[i - 2048];
        else if (i < 2560) bias_ws[i] = db1i[i - 2304] + db1h[i - 2304];
    }
}

// h0[m][64] = relu(x[m][:256] @ inW^T + in_b), m = b*100 + t  (102400 rows)
__global__ __launch_bounds__(256) void inproj_kernel(
    const float* __restrict__ x, const f16* __restrict__ pkInW,
    const float* __restrict__ in_b, f16* __restrict__ h0)
{
    int m0 = blockIdx.x * 16;
    int tid = threadIdx.x;
    int l = tid & 63, w = tid >> 6;   // 4 waves, wave w -> n-tile w
    int p = l & 15, q = l >> 4;
    f32x4 acc = {0.f, 0.f, 0.f, 0.f};
    const float* xrow = x + (long)(m0 + p) * 256 + q * 8;
    const f16x8* bp = (const f16x8*)pkInW + w * 8 * 64 + l;
    #pragma unroll
    for (int kt = 0; kt < 8; ++kt) {
        const float4* xa = (const float4*)(xrow + kt * 32);
        float4 x0 = xa[0], x1 = xa[1];
        f16x8 a = {(f16)x0.x, (f16)x0.y, (f16)x0.z, (f16)x0.w,
                   (f16)x1.x, (f16)x1.y, (f16)x1.z, (f16)x1.w};
        f16x8 b = bp[kt * 64];
        acc = MFMA16(a, b, acc);
    }
    int n = w * 16 + p;
    float bn = in_b[n];
    #pragma unroll
    for (int r = 0; r < 4; ++r) {
        float v = acc[r] + bn;
        v = v > 0.f ? v : 0.f;
        h0[(long)(m0 + q * 4 + r) * 64 + n] = (f16)v;
    }
}

// Persistent LSTM layer: 64 blocks x 512 threads (8 waves), block owns 16 batch rows for all T.
// Wave w (0..7) owns j-slices {w, w+8} (each 16 wide) across all 4 gates -> 8 n-tiles/wave,
// i,f,g,o stay in-lane for the pointwise.
// h kept in LDS in fragment-major order: element (m=b, k=j) at [(k>>5)*64 + ((k>>3)&3)*16 + m]*8 + (k&7)
//
// 2 waves/SIMD (256-VGPR budget) + explicit distance-2 rotating operand pipeline,
// pinned with sched_barrier(0) so the scheduler cannot sink the loads back onto
// their uses (round-1 failure mode: VGPR stayed 64, chain fully serialized).
// Steady state keeps 2 stages x 9 frags x 1KB = 18KB/wave (144KB/CU) in flight.
template <int KTX, bool WSEQ>
__global__ __launch_bounds__(512, 2) void lstm_enc_kernel(
    const f16* __restrict__ xseq,   // [1024][100][KTX*32] f16
    const f16* __restrict__ pkW,    // NT=64, KT=KTX+8
    const float* __restrict__ bias, // [1024] (bi+bh)
    f16* __restrict__ hseq_out,     // [1024][100][256] if WSEQ
    f16* __restrict__ z_out)        // [1024][256] if !WSEQ
{
    constexpr int KT = KTX + 8;
    constexpr int T = 100;
    constexpr int XG = KTX * 4;      // x row length in f16x8 groups
    __shared__ __align__(16) f16 hfrag[8 * 64 * 8];
    int tid = threadIdx.x;
    int l = tid & 63, w = tid >> 6;  // 8 waves
    int p = l & 15, q = l >> 4;
    int b0 = blockIdx.x * 16;

    for (int i = tid; i < 4096; i += 512) hfrag[i] = (f16)0.f;

    float bs[2][4];
    #pragma unroll
    for (int s = 0; s < 2; ++s)
        #pragma unroll
        for (int g = 0; g < 4; ++g)
            bs[s][g] = bias[g * 256 + (w + 8 * s) * 16 + p];
    float c[2][4];
    #pragma unroll
    for (int s = 0; s < 2; ++s)
        #pragma unroll
        for (int r = 0; r < 4; ++r) c[s][r] = 0.f;

    const f16x8* wbase[2][4];
    #pragma unroll
    for (int s = 0; s < 2; ++s)
        #pragma unroll
        for (int g = 0; g < 4; ++g)
            wbase[s][g] = (const f16x8*)pkW + (long)((g * 16 + w + 8 * s)) * KT * 64 + l;

    __syncthreads();

#define LOADSTAGE(k, slot)                                                      \
    {                                                                           \
        abuf[slot] = ((k) < KTX)                                                \
                         ? __builtin_nontemporal_load(xp + (k) * 4)             \
                         : *(const f16x8*)&hfrag[(((k) - KTX) * 64 + l) * 8];   \
        _Pragma("unroll")                                                       \
        for (int s_ = 0; s_ < 2; ++s_)                                          \
            _Pragma("unroll")                                                   \
            for (int g_ = 0; g_ < 4; ++g_)                                      \
                wb[slot][s_][g_] = wbase[s_][g_][(k) * 64];                     \
    }

    for (int t = 0; t < T; ++t) {
        const f16x8* xp = (const f16x8*)xseq + ((long)(b0 + p) * T + t) * XG + q;
        f32x4 acc[2][4];
        #pragma unroll
        for (int s = 0; s < 2; ++s)
            #pragma unroll
            for (int g = 0; g < 4; ++g) acc[s][g] = (f32x4){0.f, 0.f, 0.f, 0.f};

        f16x8 abuf[3];
        f16x8 wb[3][2][4];
        // prologue: issue stages 0,1
        LOADSTAGE(0, 0);
        LOADSTAGE(1, 1);
        __builtin_amdgcn_sched_barrier(0);
        #pragma unroll
        for (int kt = 0; kt < KT; ++kt) {
            if (kt + 2 < KT) {
                LOADSTAGE(kt + 2, (kt + 2) % 3);   // compile-time after unroll
            }
            __builtin_amdgcn_sched_barrier(0);     // loads stay ABOVE this line
            const int cur = kt % 3;
            #pragma unroll
            for (int s = 0; s < 2; ++s)
                #pragma unroll
                for (int g = 0; g < 4; ++g)
                    acc[s][g] = MFMA16(abuf[cur], wb[cur][s][g], acc[s][g]);
            __builtin_amdgcn_sched_barrier(0);     // MFMAs stay ABOVE this line
        }
        __syncthreads();   // all h reads done before overwrite
        // pointwise, fully in-lane: lane holds i,f,g,o for (b=4q+r, j=(w+8s)*16+p)
        #pragma unroll
        for (int s = 0; s < 2; ++s) {
            int j = (w + 8 * s) * 16 + p;
            #pragma unroll
            for (int r = 0; r < 4; ++r) {
                float iv = sigmoidf_(acc[s][0][r] + bs[s][0]);
                float fv = sigmoidf_(acc[s][1][r] + bs[s][1]);
                float gv = tanhf_(acc[s][2][r] + bs[s][2]);
                float ov = sigmoidf_(acc[s][3][r] + bs[s][3]);
                float cv = fv * c[s][r] + iv * gv;
                c[s][r] = cv;
                float hv = ov * tanhf_(cv);
                f16 hb = (f16)hv;
                int b = q * 4 + r;
                hfrag[((j >> 5) * 64 + ((j >> 3) & 3) * 16 + b) * 8 + (j & 7)] = hb;
                if constexpr (WSEQ)
                    __builtin_nontemporal_store(hb, &hseq_out[((long)(b0 + b) * T + t) * 256 + j]);
            }
        }
        __syncthreads();   // h writes visible before next step's reads
    }
#undef LOADSTAGE
    if constexpr (!WSEQ) {
        for (int i = tid; i < 4096; i += 512) {
            int b = i >> 8, j = i & 255;
            z_out[(long)(b0 + b) * 256 + j] =
                hfrag[((j >> 5) * 64 + ((j >> 3) & 3) * 16 + b) * 8 + (j & 7)];
        }
    }
}

// Fused decoder: dec0 (input z, constant over t -> xz in regs) + dec1 + output projection.
// 64 blocks x 256 threads (4 waves). hdfrag holds [h_d0 | h_d1] (K=128) fragment-major.
// All recurrent weights (128 KB/block = 128 VGPR/lane) preloaded into registers
// before the t loop -> inner loop is global-free (LDS + MFMA + VALU only).
__global__ __launch_bounds__(256, 1) void lstm_dec_kernel(
    const f16* __restrict__ z,
    const f16* __restrict__ pkD0i, const f16* __restrict__ pkD0h,
    const f16* __restrict__ pkD1,  const f16* __restrict__ pkOut,
    const float* __restrict__ bd0, const float* __restrict__ bd1,
    const float* __restrict__ out_b, float* __restrict__ out)
{
    constexpr int T = 100;
    __shared__ __align__(16) f16 hdfrag[4 * 64 * 8];
    int tid = threadIdx.x;
    int l = tid & 63, w = tid >> 6;  // 4 waves, wave w -> j-slice [w*16, w*16+16)
    int p = l & 15, q = l >> 4;
    int b0 = blockIdx.x * 16;

    for (int i = tid; i < 2048; i += 256) hdfrag[i] = (f16)0.f;

    // resident weights (t-invariant): W0h 8 frags, W1 16 frags, WO 8 frags = 128 VGPRs
    f16x8 W0h[2][4], W1[4][4], WO[2][4];
    #pragma unroll
    for (int g = 0; g < 4; ++g) {
        #pragma unroll
        for (int kt = 0; kt < 2; ++kt)
            W0h[kt][g] = ((const f16x8*)pkD0h)[(((g * 4 + w) * 2 + kt) * 64) + l];
        #pragma unroll
        for (int kt = 0; kt < 4; ++kt)
            W1[kt][g] = ((const f16x8*)pkD1)[(((g * 4 + w) * 4 + kt) * 64) + l];
    }
    #pragma unroll
    for (int i = 0; i < 4; ++i)
        #pragma unroll
        for (int kt = 0; kt < 2; ++kt)
            WO[kt][i] = ((const f16x8*)pkOut)[(((w * 4 + i) * 2 + kt) * 64) + l];

    // xz = z @ dW0i^T + bd0  (constant over t), kept in registers
    f32x4 xz[4];
    #pragma unroll
    for (int g = 0; g < 4; ++g) xz[g] = (f32x4){0.f, 0.f, 0.f, 0.f};
    {
        const f16x8* zp = (const f16x8*)z + (long)(b0 + p) * 32 + q;
        const f16x8* wp = (const f16x8*)pkD0i + l;
        #pragma unroll
        for (int kt = 0; kt < 8; ++kt) {
            f16x8 a = zp[kt * 4];
            #pragma unroll
            for (int g = 0; g < 4; ++g)
                xz[g] = MFMA16(a, wp[((g * 4 + w) * 8 + kt) * 64], xz[g]);
        }
        #pragma unroll
        for (int g = 0; g < 4; ++g) {
            float bb = bd0[g * 64 + w * 16 + p];
            #pragma unroll
            for (int r = 0; r < 4; ++r) xz[g][r] += bb;
        }
    }
    float bs1[4], bso[4];
    #pragma unroll
    for (int g = 0; g < 4; ++g) bs1[g] = bd1[g * 64 + w * 16 + p];
    #pragma unroll
    for (int i = 0; i < 4; ++i) bso[i] = out_b[(w * 4 + i) * 16 + p];
    float c0[4] = {0.f, 0.f, 0.f, 0.f}, c1[4] = {0.f, 0.f, 0.f, 0.f};
    __syncthreads();

    for (int t = 0; t < T; ++t) {
        // dec0 gates: K=64 (h_d0 in hdfrag kt 0..1)
        f32x4 acc[4];
        #pragma unroll
        for (int g = 0; g < 4; ++g) acc[g] = (f32x4){0.f, 0.f, 0.f, 0.f};
        #pragma unroll
        for (int kt = 0; kt < 2; ++kt) {
            f16x8 a = *(const f16x8*)&hdfrag[(kt * 64 + l) * 8];
            #pragma unroll
            for (int g = 0; g < 4; ++g)
                acc[g] = MFMA16(a, W0h[kt][g], acc[g]);
        }
        __syncthreads();
        #pragma unroll
        for (int r = 0; r < 4; ++r) {
            float iv = sigmoidf_(acc[0][r] + xz[0][r]);
            float fv = sigmoidf_(acc[1][r] + xz[1][r]);
            float gv = tanhf_(acc[2][r] + xz[2][r]);
            float ov = sigmoidf_(acc[3][r] + xz[3][r]);
            float cv = fv * c0[r] + iv * gv; c0[r] = cv;
            float hv = ov * tanhf_(cv);
            int j = w * 16 + p, b = q * 4 + r;   // k = j in 0..63
            hdfrag[((j >> 5) * 64 + ((j >> 3) & 3) * 16 + b) * 8 + (j & 7)] = (f16)hv;
        }
        __syncthreads();
        // dec1 gates: K=128 ([h_d0|h_d1], hdfrag kt 0..3)
        f32x4 acc1[4];
        #pragma unroll
        for (int g = 0; g < 4; ++g) acc1[g] = (f32x4){0.f, 0.f, 0.f, 0.f};
        #pragma unroll
        for (int kt = 0; kt < 4; ++kt) {
            f16x8 a = *(const f16x8*)&hdfrag[(kt * 64 + l) * 8];
            #pragma unroll
            for (int g = 0; g < 4; ++g)
                acc1[g] = MFMA16(a, W1[kt][g], acc1[g]);
        }
        __syncthreads();
        #pragma unroll
        for (int r = 0; r < 4; ++r) {
            float iv = sigmoidf_(acc1[0][r] + bs1[0]);
            float fv = sigmoidf_(acc1[1][r] + bs1[1]);
            float gv = tanhf_(acc1[2][r] + bs1[2]);
            float ov = sigmoidf_(acc1[3][r] + bs1[3]);
            float cv = fv * c1[r] + iv * gv; c1[r] = cv;
            float hv = ov * tanhf_(cv);
            int j = w * 16 + p, b = q * 4 + r;
            int k = 64 + j;                      // h_d1 lives at k 64..127
            hdfrag[((k >> 5) * 64 + ((k >> 3) & 3) * 16 + b) * 8 + (k & 7)] = (f16)hv;
        }
        __syncthreads();
        // output projection: out_t = h_d1 @ outW^T + out_b (hdfrag kt 2..3)
        f32x4 acco[4];
        #pragma unroll
        for (int i = 0; i < 4; ++i) acco[i] = (f32x4){0.f, 0.f, 0.f, 0.f};
        #pragma unroll
        for (int kt = 0; kt < 2; ++kt) {
            f16x8 a = *(const f16x8*)&hdfrag[((2 + kt) * 64 + l) * 8];
            #pragma unroll
            for (int i = 0; i < 4; ++i)
                acco[i] = MFMA16(a, WO[kt][i], acco[i]);
        }
        #pragma unroll
        for (int i = 0; i < 4; ++i)
            #pragma unroll
            for (int r = 0; r < 4; ++r)
                __builtin_nontemporal_store(acco[i][r] + bso[i],
                    &out[((long)(b0 + q * 4 + r) * T + t) * 256 + (w * 4 + i) * 16 + p]);
    }
}

extern "C" void kernel_launch(void* const* d_in, const int* in_sizes, int n_in,
                              void* d_out, int out_size, void* d_ws, size_t ws_size,
                              hipStream_t stream)
{
    const float* x    = (const float*)d_in[0];
    const float* inW  = (const float*)d_in[1];
    const float* inb  = (const float*)d_in[2];
    const float* e0i  = (const float*)d_in[3];
    const float* e0h  = (const float*)d_in[4];
    const float* eb0i = (const float*)d_in[5];
    const float* eb0h = (const float*)d_in[6];
    const float* e1i  = (const float*)d_in[7];
    const float* e1h  = (const float*)d_in[8];
    const float* eb1i = (const float*)d_in[9];
    const float* eb1h = (const float*)d_in[10];
    const float* d0i  = (const float*)d_in[11];
    const float* d0h  = (const float*)d_in[12];
    const float* db0i = (const float*)d_in[13];
    const float* db0h = (const float*)d_in[14];
    const float* d1i  = (const float*)d_in[15];
    const float* d1h  = (const float*)d_in[16];
    const float* db1i = (const float*)d_in[17];
    const float* db1h = (const float*)d_in[18];
    const float* outW = (const float*)d_in[19];
    const float* outb = (const float*)d_in[20];

    char* ws = (char*)d_ws;
    f16*   pk     = (f16*)ws;
    float* biases = (float*)(ws + BIAS_OFF);
    f16*   h0     = (f16*)(ws + H0_OFF);
    f16*   h1     = (f16*)(ws + H1_OFF);
    f16*   zb     = (f16*)(ws + Z_OFF);
    float* out    = (float*)d_out;

    pack_kernel<<<498, 256, 0, stream>>>(inW, e0i, e0h, e1i, e1h, d0i, d0h, d1i, d1h, outW,
                                         eb0i, eb0h, eb1i, eb1h, db0i, db0h, db1i, db1h,
                                         pk, biases);
    inproj_kernel<<<6400, 256, 0, stream>>>(x, pk, inb, h0);
    lstm_enc_kernel<2, true ><<<64, 512, 0, stream>>>(h0, pk + 16384, biases, h1, nullptr);
    lstm_enc_kernel<8, false><<<64, 512, 0, stream>>>(h1, pk + 344064, biases + 1024, nullptr, zb);
    lstm_dec_kernel<<<64, 256, 0, stream>>>(zb, pk + 868352, pk + 933888, pk + 950272, pk + 983040,
                                            biases + 2048, biases + 2304, outb, out);
}

// Round 3
// 4135.530 us; speedup vs baseline: 1.1202x; 1.1202x over previous
//
#include <hip/hip_runtime.h>

typedef _Float16 f16;
typedef _Float16 f16x8 __attribute__((ext_vector_type(8)));
typedef float f32x4 __attribute__((ext_vector_type(4)));

#define MFMA16(a, b, c) __builtin_amdgcn_mfma_f32_16x16x32_f16((a), (b), (c), 0, 0, 0)

__device__ __forceinline__ float sigmoidf_(float x) { return 1.f / (1.f + __expf(-x)); }
__device__ __forceinline__ float tanhf_(float x) { return 1.f - 2.f / (__expf(2.f * x) + 1.f); }

// async global->LDS, 16B per lane; LDS dest is wave-uniform base + lane*16
__device__ __forceinline__ void gl_lds16(const void* g, void* l) {
    __builtin_amdgcn_global_load_lds(
        (__attribute__((address_space(1))) const unsigned int*)g,
        (__attribute__((address_space(3))) unsigned int*)l, 16, 0, 0);
}

// ---------------- workspace layout (bytes) ----------------
// packed fp16 weights (element offsets within pk):
//   inW 0 | e0 16384 | e1 344064 | d0i 868352 | d0h 933888 | d1 950272 | out 983040 | end 999424
#define PK_BYTES   1998848
#define BIAS_OFF   1998848   // 2560 floats: be0[1024] be1[1024] bd0[256] bd1[256]
#define H0_OFF     2009088   // 1024*100*64 f16
#define H1_OFF     15116288  // 1024*100*256 f16
#define Z_OFF      67545088  // 1024*256 f16

// Fragment layout: frag(nt, kt, lane) holds n = nt*16 + (lane&15),
// k = kt*32 + (lane>>4)*8 + j  (gfx950 16x16x32 A/B layout).
//
// Packing order per region:
//  - nt-major (inW, d0i, d0h, d1, out): group g = (nt*KT + kt)*64 + lane  (unchanged)
//  - k-major, stream order (e0, e1): stage si = (kt>=KTX)? kt-KTX : kt+8  (h-stages first),
//    frag at ((si*64 + nt)*64 + lane)*8.  One stage = contiguous 64KB -> global_load_lds.

__global__ __launch_bounds__(256) void pack_kernel(
    const float* inW,
    const float* e0i, const float* e0h, const float* e1i, const float* e1h,
    const float* d0i, const float* d0h, const float* d1i, const float* d1h,
    const float* outW,
    const float* eb0i, const float* eb0h, const float* eb1i, const float* eb1h,
    const float* db0i, const float* db0h, const float* db1i, const float* db1h,
    f16* pk, float* bias_ws)
{
    int t = blockIdx.x * 256 + threadIdx.x;
    if (t < 124928) {
        int g = t; int KT, ka, kb, ktx; const float* A; const float* B; long doff;
        if (g < 2048)        {              KT = 8;  ka = 256; kb = 0;   ktx = -1; A = inW;  B = nullptr; doff = 0; }
        else if (g < 43008)  { g -= 2048;   KT = 10; ka = 64;  kb = 256; ktx = 2;  A = e0i;  B = e0h;     doff = 16384; }
        else if (g < 108544) { g -= 43008;  KT = 16; ka = 256; kb = 256; ktx = 8;  A = e1i;  B = e1h;     doff = 344064; }
        else if (g < 116736) { g -= 108544; KT = 8;  ka = 256; kb = 0;   ktx = -1; A = d0i;  B = nullptr; doff = 868352; }
        else if (g < 118784) { g -= 116736; KT = 2;  ka = 64;  kb = 0;   ktx = -1; A = d0h;  B = nullptr; doff = 933888; }
        else if (g < 122880) { g -= 118784; KT = 4;  ka = 64;  kb = 64;  ktx = -1; A = d1i;  B = d1h;     doff = 950272; }
        else                 { g -= 122880; KT = 2;  ka = 64;  kb = 0;   ktx = -1; A = outW; B = nullptr; doff = 983040; }
        int lane = g & 63; int gk = g >> 6;
        int kt = gk % KT;  int nt = gk / KT;
        int n  = nt * 16 + (lane & 15);
        int k0 = kt * 32 + (lane >> 4) * 8;
        f16x8 v;
        #pragma unroll
        for (int j = 0; j < 8; ++j) {
            int k = k0 + j;
            float s = (k < ka) ? A[(long)n * ka + k] : B[(long)n * kb + (k - ka)];
            v[j] = (f16)s;
        }
        long off;
        if (ktx >= 0) {
            int si = (kt >= ktx) ? (kt - ktx) : (kt + 8);
            off = doff + ((long)(si * 64 + nt) * 64 + lane) * 8;
        } else {
            off = doff + (long)g * 8;
        }
        *(f16x8*)(pk + off) = v;
    } else {
        int i = t - 124928;
        if (i < 1024)      bias_ws[i] = eb0i[i] + eb0h[i];
        else if (i < 2048) bias_ws[i] = eb1i[i - 1024] + eb1h[i - 1024];
        else if (i < 2304) bias_ws[i] = db0i[i - 2048] + db0h[i - 2048];
        else if (i < 2560) bias_ws[i] = db1i[i - 2304] + db1h[i - 2304];
    }
}

// h0[m][64] = relu(x[m][:256] @ inW^T + in_b), m = b*100 + t  (102400 rows)
__global__ __launch_bounds__(256) void inproj_kernel(
    const float* __restrict__ x, const f16* __restrict__ pkInW,
    const float* __restrict__ in_b, f16* __restrict__ h0)
{
    int m0 = blockIdx.x * 16;
    int tid = threadIdx.x;
    int l = tid & 63, w = tid >> 6;   // 4 waves, wave w -> n-tile w
    int p = l & 15, q = l >> 4;
    f32x4 acc = {0.f, 0.f, 0.f, 0.f};
    const float* xrow = x + (long)(m0 + p) * 256 + q * 8;
    const f16x8* bp = (const f16x8*)pkInW + w * 8 * 64 + l;
    #pragma unroll
    for (int kt = 0; kt < 8; ++kt) {
        const float4* xa = (const float4*)(xrow + kt * 32);
        float4 x0 = xa[0], x1 = xa[1];
        f16x8 a = {(f16)x0.x, (f16)x0.y, (f16)x0.z, (f16)x0.w,
                   (f16)x1.x, (f16)x1.y, (f16)x1.z, (f16)x1.w};
        f16x8 b = bp[kt * 64];
        acc = MFMA16(a, b, acc);
    }
    int n = w * 16 + p;
    float bn = in_b[n];
    #pragma unroll
    for (int r = 0; r < 4; ++r) {
        float v = acc[r] + bn;
        v = v > 0.f ? v : 0.f;
        h0[(long)(m0 + q * 4 + r) * 64 + n] = (f16)v;
    }
}

// Persistent LSTM layer: 64 blocks x 1024 threads (16 waves, 4/SIMD), block owns
// 16 batch rows for all T.  Wave w owns j-slice [w*16,w*16+16) across all 4 gates
// (n-tiles {w, 16+w, 32+w, 48+w}) -> i,f,g,o in-lane for the pointwise.
//
// Weight stream (1MB/ts for enc1) goes through a 2 x 64KB LDS double buffer via
// global_load_lds (width 16): per K-stage, 1024 threads x 16B x 4 issues = 64KB.
// Stage si+1 is issued before computing stage si; one __syncthreads per stage
// drains it (m97 GEMM structure).  In-flight bytes live in the VMEM queue + LDS,
// not VGPRs (rounds 1-2 showed register pipelines can't cover the latency).
// Stages are ordered h-first so the per-ts x-fragment register loads have ~8
// stages to land before first use; next-ts stage 0 is prefetched across the
// pointwise phase.
// h kept in LDS fragment-major: element (m=b, k=j) at
//   [(k>>5)*64 + ((k>>3)&3)*16 + m]*8 + (k&7)
template <int KTX, bool WSEQ>
__global__ __launch_bounds__(1024, 4) void lstm_enc_kernel(
    const f16* __restrict__ xseq,   // [1024][100][KTX*32] f16
    const f16* __restrict__ pkW,    // k-major stages: stage si at si*32768 elems (64KB)
    const float* __restrict__ bias, // [1024] (bi+bh)
    f16* __restrict__ hseq_out,     // [1024][100][256] if WSEQ
    f16* __restrict__ z_out)        // [1024][256] if !WSEQ
{
    constexpr int KT = KTX + 8;
    constexpr int T = 100;
    constexpr int XG = KTX * 4;      // x row length in f16x8 groups
    __shared__ __align__(16) f16 wbuf[2][32768];   // 2 x 64KB stage buffers
    __shared__ __align__(16) f16 hfrag[4096];      // 8KB h state
    int tid = threadIdx.x;
    int l = tid & 63, w = tid >> 6;  // 16 waves
    int p = l & 15, q = l >> 4;
    int b0 = blockIdx.x * 16;

    for (int i = tid; i < 4096; i += 1024) hfrag[i] = (f16)0.f;

    float bs[4];
    #pragma unroll
    for (int g = 0; g < 4; ++g) bs[g] = bias[g * 256 + w * 16 + p];
    float c[4] = {0.f, 0.f, 0.f, 0.f};

    const char* pkb = (const char*)pkW;
    int stoff = w * 1024;            // wave-uniform LDS dest offset within a 16KB round

    // prologue: stage 0 -> wbuf[0]
    #pragma unroll
    for (int r = 0; r < 4; ++r)
        gl_lds16(pkb + r * 16384 + tid * 16, (char*)&wbuf[0][0] + r * 16384 + stoff);
    __syncthreads();

    for (int t = 0; t < T; ++t) {
        // x fragments for this ts into registers (first used at stage 8)
        f16x8 xf[KTX];
        const f16x8* xp = (const f16x8*)xseq + ((long)(b0 + p) * T + t) * XG + q;
        #pragma unroll
        for (int i = 0; i < KTX; ++i) xf[i] = __builtin_nontemporal_load(xp + i * 4);

        f32x4 acc[4];
        #pragma unroll
        for (int g = 0; g < 4; ++g) acc[g] = (f32x4){0.f, 0.f, 0.f, 0.f};

        #pragma unroll
        for (int si = 0; si < KT; ++si) {
            if (si + 1 < KT) {       // issue next stage into the other buffer
                const char* src = pkb + (long)(si + 1) * 65536;
                char* dst = (char*)&wbuf[(si + 1) & 1][0];
                #pragma unroll
                for (int r = 0; r < 4; ++r)
                    gl_lds16(src + r * 16384 + tid * 16, dst + r * 16384 + stoff);
            }
            f16x8 a;
            if (si < 8) a = *(const f16x8*)&hfrag[(si * 64 + l) * 8];  // h stage
            else        a = xf[si - 8];                                 // x stage
            const f16* bb = &wbuf[si & 1][0];
            #pragma unroll
            for (int g = 0; g < 4; ++g) {
                f16x8 bf = *(const f16x8*)&bb[((g * 16 + w) * 64 + l) * 8];
                acc[g] = MFMA16(a, bf, acc[g]);
            }
            __syncthreads();         // drains next-stage loads + orders LDS reuse
        }
        if (t + 1 < T) {             // prefetch next-ts stage 0 across the pointwise
            #pragma unroll
            for (int r = 0; r < 4; ++r)
                gl_lds16(pkb + r * 16384 + tid * 16, (char*)&wbuf[0][0] + r * 16384 + stoff);
        }
        // pointwise, fully in-lane: lane holds i,f,g,o for (b=4q+r, j=w*16+p)
        int j = w * 16 + p;
        #pragma unroll
        for (int r = 0; r < 4; ++r) {
            float iv = sigmoidf_(acc[0][r] + bs[0]);
            float fv = sigmoidf_(acc[1][r] + bs[1]);
            float gv = tanhf_(acc[2][r] + bs[2]);
            float ov = sigmoidf_(acc[3][r] + bs[3]);
            float cv = fv * c[r] + iv * gv;
            c[r] = cv;
            float hv = ov * tanhf_(cv);
            f16 hb = (f16)hv;
            int b = q * 4 + r;
            hfrag[((j >> 5) * 64 + ((j >> 3) & 3) * 16 + b) * 8 + (j & 7)] = hb;
            if constexpr (WSEQ)
                __builtin_nontemporal_store(hb, &hseq_out[((long)(b0 + b) * T + t) * 256 + j]);
        }
        __syncthreads();             // h writes + stage-0 prefetch ready for next ts
    }
    if constexpr (!WSEQ) {
        for (int i = tid; i < 4096; i += 1024) {
            int b = i >> 8, j = i & 255;
            z_out[(long)(b0 + b) * 256 + j] =
                hfrag[((j >> 5) * 64 + ((j >> 3) & 3) * 16 + b) * 8 + (j & 7)];
        }
    }
}

// Fused decoder: dec0 (input z, constant over t -> xz in regs) + dec1 + output projection.
// 64 blocks x 256 threads (4 waves). hdfrag holds [h_d0 | h_d1] (K=128) fragment-major.
// All recurrent weights (128 KB/block = 128 VGPR/lane) preloaded into registers
// before the t loop -> inner loop is global-free (LDS + MFMA + VALU only).
__global__ __launch_bounds__(256, 1) void lstm_dec_kernel(
    const f16* __restrict__ z,
    const f16* __restrict__ pkD0i, const f16* __restrict__ pkD0h,
    const f16* __restrict__ pkD1,  const f16* __restrict__ pkOut,
    const float* __restrict__ bd0, const float* __restrict__ bd1,
    const float* __restrict__ out_b, float* __restrict__ out)
{
    constexpr int T = 100;
    __shared__ __align__(16) f16 hdfrag[4 * 64 * 8];
    int tid = threadIdx.x;
    int l = tid & 63, w = tid >> 6;  // 4 waves, wave w -> j-slice [w*16, w*16+16)
    int p = l & 15, q = l >> 4;
    int b0 = blockIdx.x * 16;

    for (int i = tid; i < 2048; i += 256) hdfrag[i] = (f16)0.f;

    // resident weights (t-invariant): W0h 8 frags, W1 16 frags, WO 8 frags = 128 VGPRs
    f16x8 W0h[2][4], W1[4][4], WO[2][4];
    #pragma unroll
    for (int g = 0; g < 4; ++g) {
        #pragma unroll
        for (int kt = 0; kt < 2; ++kt)
            W0h[kt][g] = ((const f16x8*)pkD0h)[(((g * 4 + w) * 2 + kt) * 64) + l];
        #pragma unroll
        for (int kt = 0; kt < 4; ++kt)
            W1[kt][g] = ((const f16x8*)pkD1)[(((g * 4 + w) * 4 + kt) * 64) + l];
    }
    #pragma unroll
    for (int i = 0; i < 4; ++i)
        #pragma unroll
        for (int kt = 0; kt < 2; ++kt)
            WO[kt][i] = ((const f16x8*)pkOut)[(((w * 4 + i) * 2 + kt) * 64) + l];

    // xz = z @ dW0i^T + bd0  (constant over t), kept in registers
    f32x4 xz[4];
    #pragma unroll
    for (int g = 0; g < 4; ++g) xz[g] = (f32x4){0.f, 0.f, 0.f, 0.f};
    {
        const f16x8* zp = (const f16x8*)z + (long)(b0 + p) * 32 + q;
        const f16x8* wp = (const f16x8*)pkD0i + l;
        #pragma unroll
        for (int kt = 0; kt < 8; ++kt) {
            f16x8 a = zp[kt * 4];
            #pragma unroll
            for (int g = 0; g < 4; ++g)
                xz[g] = MFMA16(a, wp[((g * 4 + w) * 8 + kt) * 64], xz[g]);
        }
        #pragma unroll
        for (int g = 0; g < 4; ++g) {
            float bb = bd0[g * 64 + w * 16 + p];
            #pragma unroll
            for (int r = 0; r < 4; ++r) xz[g][r] += bb;
        }
    }
    float bs1[4], bso[4];
    #pragma unroll
    for (int g = 0; g < 4; ++g) bs1[g] = bd1[g * 64 + w * 16 + p];
    #pragma unroll
    for (int i = 0; i < 4; ++i) bso[i] = out_b[(w * 4 + i) * 16 + p];
    float c0[4] = {0.f, 0.f, 0.f, 0.f}, c1[4] = {0.f, 0.f, 0.f, 0.f};
    __syncthreads();

    for (int t = 0; t < T; ++t) {
        // dec0 gates: K=64 (h_d0 in hdfrag kt 0..1)
        f32x4 acc[4];
        #pragma unroll
        for (int g = 0; g < 4; ++g) acc[g] = (f32x4){0.f, 0.f, 0.f, 0.f};
        #pragma unroll
        for (int kt = 0; kt < 2; ++kt) {
            f16x8 a = *(const f16x8*)&hdfrag[(kt * 64 + l) * 8];
            #pragma unroll
            for (int g = 0; g < 4; ++g)
                acc[g] = MFMA16(a, W0h[kt][g], acc[g]);
        }
        __syncthreads();
        #pragma unroll
        for (int r = 0; r < 4; ++r) {
            float iv = sigmoidf_(acc[0][r] + xz[0][r]);
            float fv = sigmoidf_(acc[1][r] + xz[1][r]);
            float gv = tanhf_(acc[2][r] + xz[2][r]);
            float ov = sigmoidf_(acc[3][r] + xz[3][r]);
            float cv = fv * c0[r] + iv * gv; c0[r] = cv;
            float hv = ov * tanhf_(cv);
            int j = w * 16 + p, b = q * 4 + r;   // k = j in 0..63
            hdfrag[((j >> 5) * 64 + ((j >> 3) & 3) * 16 + b) * 8 + (j & 7)] = (f16)hv;
        }
        __syncthreads();
        // dec1 gates: K=128 ([h_d0|h_d1], hdfrag kt 0..3)
        f32x4 acc1[4];
        #pragma unroll
        for (int g = 0; g < 4; ++g) acc1[g] = (f32x4){0.f, 0.f, 0.f, 0.f};
        #pragma unroll
        for (int kt = 0; kt < 4; ++kt) {
            f16x8 a = *(const f16x8*)&hdfrag[(kt * 64 + l) * 8];
            #pragma unroll
            for (int g = 0; g < 4; ++g)
                acc1[g] = MFMA16(a, W1[kt][g], acc1[g]);
        }
        __syncthreads();
        #pragma unroll
        for (int r = 0; r < 4; ++r) {
            float iv = sigmoidf_(acc1[0][r] + bs1[0]);
            float fv = sigmoidf_(acc1[1][r] + bs1[1]);
            float gv = tanhf_(acc1[2][r] + bs1[2]);
            float ov = sigmoidf_(acc1[3][r] + bs1[3]);
            float cv = fv * c1[r] + iv * gv; c1[r] = cv;
            float hv = ov * tanhf_(cv);
            int j = w * 16 + p, b = q * 4 + r;
            int k = 64 + j;                      // h_d1 lives at k 64..127
            hdfrag[((k >> 5) * 64 + ((k >> 3) & 3) * 16 + b) * 8 + (k & 7)] = (f16)hv;
        }
        __syncthreads();
        // output projection: out_t = h_d1 @ outW^T + out_b (hdfrag kt 2..3)
        f32x4 acco[4];
        #pragma unroll
        for (int i = 0; i < 4; ++i) acco[i] = (f32x4){0.f, 0.f, 0.f, 0.f};
        #pragma unroll
        for (int kt = 0; kt < 2; ++kt) {
            f16x8 a = *(const f16x8*)&hdfrag[((2 + kt) * 64 + l) * 8];
            #pragma unroll
            for (int i = 0; i < 4; ++i)
                acco[i] = MFMA16(a, WO[kt][i], acco[i]);
        }
        #pragma unroll
        for (int i = 0; i < 4; ++i)
            #pragma unroll
            for (int r = 0; r < 4; ++r)
                __builtin_nontemporal_store(acco[i][r] + bso[i],
                    &out[((long)(b0 + q * 4 + r) * T + t) * 256 + (w * 4 + i) * 16 + p]);
    }
}

extern "C" void kernel_launch(void* const* d_in, const int* in_sizes, int n_in,
                              void* d_out, int out_size, void* d_ws, size_t ws_size,
                              hipStream_t stream)
{
    const float* x    = (const float*)d_in[0];
    const float* inW  = (const float*)d_in[1];
    const float* inb  = (const float*)d_in[2];
    const float* e0i  = (const float*)d_in[3];
    const float* e0h  = (const float*)d_in[4];
    const float* eb0i = (const float*)d_in[5];
    const float* eb0h = (const float*)d_in[6];
    const float* e1i  = (const float*)d_in[7];
    const float* e1h  = (const float*)d_in[8];
    const float* eb1i = (const float*)d_in[9];
    const float* eb1h = (const float*)d_in[10];
    const float* d0i  = (const float*)d_in[11];
    const float* d0h  = (const float*)d_in[12];
    const float* db0i = (const float*)d_in[13];
    const float* db0h = (const float*)d_in[14];
    const float* d1i  = (const float*)d_in[15];
    const float* d1h  = (const float*)d_in[16];
    const float* db1i = (const float*)d_in[17];
    const float* db1h = (const float*)d_in[18];
    const float* outW = (const float*)d_in[19];
    const float* outb = (const float*)d_in[20];

    char* ws = (char*)d_ws;
    f16*   pk     = (f16*)ws;
    float* biases = (float*)(ws + BIAS_OFF);
    f16*   h0     = (f16*)(ws + H0_OFF);
    f16*   h1     = (f16*)(ws + H1_OFF);
    f16*   zb     = (f16*)(ws + Z_OFF);
    float* out    = (float*)d_out;

    pack_kernel<<<498, 256, 0, stream>>>(inW, e0i, e0h, e1i, e1h, d0i, d0h, d1i, d1h, outW,
                                         eb0i, eb0h, eb1i, eb1h, db0i, db0h, db1i, db1h,
                                         pk, biases);
    inproj_kernel<<<6400, 256, 0, stream>>>(x, pk, inb, h0);
    lstm_enc_kernel<2, true ><<<64, 1024, 0, stream>>>(h0, pk + 16384, biases, h1, nullptr);
    lstm_enc_kernel<8, false><<<64, 1024, 0, stream>>>(h1, pk + 344064, biases + 1024, nullptr, zb);
    lstm_dec_kernel<<<64, 256, 0, stream>>>(zb, pk + 868352, pk + 933888, pk + 950272, pk + 983040,
                                            biases + 2048, biases + 2304, outb, out);
}